// Round 1
// baseline (169.517 us; speedup 1.0000x reference)
//
#include <hip/hip_runtime.h>
#include <math.h>

// Geodesic loss: mean over B of acos(clip((sum_ij m1*m2 - 1)*0.5, -1, 1)).
// HBM-bound: 151 MB read. Key trick: 4 matrices = 36 floats = 9 float4 (144 B,
// 16B-aligned) -> each thread owns 4 whole matrices via 9 contiguous float4
// loads per input. Perfect line utilization, no LDS staging needed.

#define TPB 256
#define MPT 4   // matrices per thread

__device__ __forceinline__ float block_reduce(float sum) {
    // 64-wide wave shuffle reduce
    #pragma unroll
    for (int off = 32; off > 0; off >>= 1)
        sum += __shfl_down(sum, off, 64);
    __shared__ float ws[TPB / 64];
    const int lane = threadIdx.x & 63;
    const int wid  = threadIdx.x >> 6;
    if (lane == 0) ws[wid] = sum;
    __syncthreads();
    float s = 0.0f;
    if (threadIdx.x == 0) {
        #pragma unroll
        for (int i = 0; i < TPB / 64; ++i) s += ws[i];
    }
    return s;  // valid on thread 0 only
}

__global__ __launch_bounds__(TPB) void geo_partial_kernel(
    const float* __restrict__ a, const float* __restrict__ b,
    float* __restrict__ part, int M)
{
    const long long t  = (long long)blockIdx.x * TPB + threadIdx.x;
    const long long m0 = t * MPT;
    float sum = 0.0f;

    if (m0 + MPT <= M) {
        // fast path: 9 float4 per input, thread-contiguous 144B chunks
        const float4* a4 = (const float4*)a + t * 9;
        const float4* b4 = (const float4*)b + t * 9;
        float ra[36], rb[36];
        #pragma unroll
        for (int i = 0; i < 9; ++i) {
            float4 va = a4[i];
            float4 vb = b4[i];
            ra[4*i+0] = va.x; ra[4*i+1] = va.y; ra[4*i+2] = va.z; ra[4*i+3] = va.w;
            rb[4*i+0] = vb.x; rb[4*i+1] = vb.y; rb[4*i+2] = vb.z; rb[4*i+3] = vb.w;
        }
        #pragma unroll
        for (int j = 0; j < MPT; ++j) {
            float c = 0.0f;
            #pragma unroll
            for (int k = 0; k < 9; ++k)
                c = fmaf(ra[9*j+k], rb[9*j+k], c);
            float cosv = (c - 1.0f) * 0.5f;
            cosv = fminf(1.0f, fmaxf(-1.0f, cosv));
            sum += acosf(cosv);
        }
    } else {
        // tail path (unused when M % (TPB*MPT) == 0, kept for generality)
        for (int j = 0; j < MPT; ++j) {
            long long m = m0 + j;
            if (m < M) {
                float c = 0.0f;
                for (int k = 0; k < 9; ++k)
                    c = fmaf(a[m*9+k], b[m*9+k], c);
                float cosv = (c - 1.0f) * 0.5f;
                cosv = fminf(1.0f, fmaxf(-1.0f, cosv));
                sum += acosf(cosv);
            }
        }
    }

    float s = block_reduce(sum);
    if (threadIdx.x == 0) part[blockIdx.x] = s;
}

__global__ __launch_bounds__(TPB) void geo_final_kernel(
    const float* __restrict__ part, int nparts,
    float* __restrict__ out, float invM)
{
    float sum = 0.0f;
    for (int i = threadIdx.x; i < nparts; i += TPB)
        sum += part[i];
    float s = block_reduce(sum);
    if (threadIdx.x == 0) out[0] = s * invM;
}

extern "C" void kernel_launch(void* const* d_in, const int* in_sizes, int n_in,
                              void* d_out, int out_size, void* d_ws, size_t ws_size,
                              hipStream_t stream) {
    const float* a = (const float*)d_in[0];
    const float* b = (const float*)d_in[1];
    float* out  = (float*)d_out;
    float* part = (float*)d_ws;

    const int n = in_sizes[0];       // flat float count = 9*M
    const int M = n / 9;             // number of 3x3 matrices

    const int nthreads = (M + MPT - 1) / MPT;
    const int grid     = (nthreads + TPB - 1) / TPB;   // 2048 for B=2^21

    geo_partial_kernel<<<grid, TPB, 0, stream>>>(a, b, part, M);
    geo_final_kernel<<<1, TPB, 0, stream>>>(part, grid, out, 1.0f / (float)M);
}